// Round 11
// baseline (149.897 us; speedup 1.0000x reference)
//
#include <hip/hip_runtime.h>
#include <math.h>

#define MUL_S 64
#define MUL_V 32
#define FEAT  160          // 64 + 3*32
#define VN    2000
#define NN    200000
#define NGRP16 (NN / 16)   // 12500 groups of 16 nodes (one wave each)
#define XSTR  168          // bf16 elems per LDS row (336 B)

#define INV8         0.125f
#define INV_SQRT32   0.17677669529663687f
#define INV_SQRT3    0.57735026918962576f
#define INV_SQRT96   0.10206207261596575f
#define INV_S3S96    0.05892556509887896f   /* 1/(sqrt(3)*sqrt(96)) */
#define INV_SQRT2    0.70710678118654752f
#define INV_SQRT_AVG 0.1f

typedef __attribute__((ext_vector_type(8))) short bf16x8;   // 8 bf16 = 4 VGPR
typedef __attribute__((ext_vector_type(4))) float f32x4;    // acc frag

#define MFMA(a, b, c) __builtin_amdgcn_mfma_f32_16x16x32_bf16((a), (b), (c), 0, 0, 0)

__device__ __forceinline__ short f2bf(float f) {
    union { float f; unsigned u; } c; c.f = f;
    unsigned r = c.u + 0x7FFFu + ((c.u >> 16) & 1u);   // round-nearest-even
    return (short)(r >> 16);
}
__device__ __forceinline__ float bf2f(short s) {
    union { unsigned u; float f; } c; c.u = ((unsigned)(unsigned short)s) << 16;
    return c.f;
}
__device__ __forceinline__ float silu_n(float x) {
    return x * (1.0f / (1.0f + __expf(-x))) * 1.679059f;
}

// B-fragment for 16x16x32: lane holds col = (lane&15)+16*nt of W, k = lhi*8+e.
__device__ __forceinline__ bf16x8 load_bfrag(const float* __restrict__ W, int N,
                                             int kbase, int col, int lhi) {
    const float* p = W + (size_t)(kbase + lhi * 8) * N + col;
    bf16x8 b;
#pragma unroll
    for (int e = 0; e < 8; ++e) b[e] = f2bf(p[(size_t)e * N]);
    return b;
}

// ---------------------------------------------------------------------------
// K1 (R11): BARRIER-FREE, 1 wave / 16-node group.
// Evidence: R5/R7/R8/R9/R10 all ~91-123us regardless of staging scheme;
// R8's +1 barrier cost +30us -> the barrier-phased lockstep chain (each
// __syncthreads drains vmcnt incl. ~1000 scan atomics) at 2 blocks/CU was
// the bottleneck, not memory latency. One wave owns the whole 16-row tile:
// stage -> MFMA -> epilogue -> scan with ZERO barriers (wave-synchronous
// LDS; sched_barrier(0) pins compiler ordering). LDS 16KB -> 10 waves/CU,
// all independent.
// ---------------------------------------------------------------------------
__global__ __launch_bounds__(64) void k1_msg(
    const float* __restrict__ x_node, const float* __restrict__ sh,
    const float* __restrict__ WA, const float* __restrict__ WB,
    const float* __restrict__ WC, const float* __restrict__ WD,
    const int* __restrict__ batch, float* __restrict__ m_acc)
{
    __shared__ short xbf[16 * XSTR] __attribute__((aligned(16)));   // 5376 B
    __shared__ float mt[16][FEAT + 1];                              // 10304 B
    __shared__ float shs[16][4];
    __shared__ int   bs[16];

    const int lane = threadIdx.x;       // 0..63
    const int lrow = lane & 15, lhi = lane >> 4;

    bf16x8 bWA[4][2], bWB[4], bWC[2], bWD[2][2];
#pragma unroll
    for (int nt = 0; nt < 4; ++nt) {
        bWA[nt][0] = load_bfrag(WA, 64, 0,  lrow + 16 * nt, lhi);
        bWA[nt][1] = load_bfrag(WA, 64, 32, lrow + 16 * nt, lhi);
        bWB[nt]    = load_bfrag(WB, 64, 0,  lrow + 16 * nt, lhi);
    }
#pragma unroll
    for (int nt = 0; nt < 2; ++nt) {
        bWC[nt]    = load_bfrag(WC, 32, 0,  lrow + 16 * nt, lhi);
        bWD[nt][0] = load_bfrag(WD, 32, 0,  lrow + 16 * nt, lhi);
        bWD[nt][1] = load_bfrag(WD, 32, 32, lrow + 16 * nt, lhi);
    }

    for (int g0 = blockIdx.x; g0 < NGRP16; g0 += gridDim.x) {
        const int n0 = g0 * 16;
        __builtin_amdgcn_sched_barrier(0);   // fence vs previous iteration

        // ---- stage 16x160 tile: 640 float4, 10 per lane ----
        if (lane < 16) bs[lane] = batch[n0 + lane];
        shs[lane >> 2][lane & 3] = sh[(size_t)n0 * 4 + lane];
        {
            const float4* xb4 = (const float4*)(x_node + (size_t)n0 * FEAT);
#pragma unroll
            for (int it = 0; it < 10; ++it) {
                int i4 = lane + it * 64;
                float4 v = xb4[i4];
                int row = i4 / 40;
                int c0  = (i4 - row * 40) * 4;
                if (c0 < MUL_S) {
                    short4 s4;
                    s4.x = f2bf(v.x); s4.y = f2bf(v.y); s4.z = f2bf(v.z); s4.w = f2bf(v.w);
                    *(short4*)&xbf[row * XSTR + c0] = s4;
                } else {
                    int t = c0 - MUL_S;
                    xbf[row * XSTR + MUL_S + ((t + 0) % 3) * 32 + (t + 0) / 3] = f2bf(v.x);
                    xbf[row * XSTR + MUL_S + ((t + 1) % 3) * 32 + (t + 1) / 3] = f2bf(v.y);
                    xbf[row * XSTR + MUL_S + ((t + 2) % 3) * 32 + (t + 2) / 3] = f2bf(v.z);
                    xbf[row * XSTR + MUL_S + ((t + 3) % 3) * 32 + (t + 3) / 3] = f2bf(v.w);
                }
            }
        }
        __builtin_amdgcn_sched_barrier(0);   // LDS writes precede frag reads (wave in-order)

        // ---- A-frags ----
        const int arow = lrow * XSTR + lhi * 8;
        bf16x8 aS0 = *(const bf16x8*)&xbf[arow];
        bf16x8 aS1 = *(const bf16x8*)&xbf[arow + 32];
        bf16x8 aV0 = *(const bf16x8*)&xbf[arow + 64];
        bf16x8 aV1 = *(const bf16x8*)&xbf[arow + 96];
        bf16x8 aV2 = *(const bf16x8*)&xbf[arow + 128];
        bf16x8 aDot;
        {
            float s1a = shs[lrow][1], s1b = shs[lrow][2], s1c = shs[lrow][3];
#pragma unroll
            for (int e = 0; e < 8; ++e)
                aDot[e] = f2bf((bf2f(aV0[e]) * s1a + bf2f(aV1[e]) * s1b +
                                bf2f(aV2[e]) * s1c) * INV_SQRT3);
        }

        f32x4 accA[4], accB[4], accD[2], accC0[2], accC1[2], accC2[2];
#pragma unroll
        for (int nt = 0; nt < 4; ++nt) { accA[nt] = (f32x4){0,0,0,0}; accB[nt] = (f32x4){0,0,0,0}; }
#pragma unroll
        for (int nt = 0; nt < 2; ++nt) { accD[nt] = (f32x4){0,0,0,0};
            accC0[nt] = (f32x4){0,0,0,0}; accC1[nt] = (f32x4){0,0,0,0}; accC2[nt] = (f32x4){0,0,0,0}; }

#pragma unroll
        for (int nt = 0; nt < 4; ++nt) {
            accA[nt] = MFMA(aS0, bWA[nt][0], accA[nt]);
            accA[nt] = MFMA(aS1, bWA[nt][1], accA[nt]);
            accB[nt] = MFMA(aDot, bWB[nt], accB[nt]);
        }
#pragma unroll
        for (int nt = 0; nt < 2; ++nt) {
            accD[nt]  = MFMA(aS0, bWD[nt][0], accD[nt]);
            accD[nt]  = MFMA(aS1, bWD[nt][1], accD[nt]);
            accC0[nt] = MFMA(aV0, bWC[nt], accC0[nt]);
            accC1[nt] = MFMA(aV1, bWC[nt], accC1[nt]);
            accC2[nt] = MFMA(aV2, bWC[nt], accC2[nt]);
        }

        // ---- epilogue -> mt (rows lhi*4+q, verified C/D layout) ----
        float sh0q[4], sh1q[4][3];
#pragma unroll
        for (int q = 0; q < 4; ++q) {
            int rr = lhi * 4 + q;
            sh0q[q] = shs[rr][0];
            sh1q[q][0] = shs[rr][1]; sh1q[q][1] = shs[rr][2]; sh1q[q][2] = shs[rr][3];
        }
#pragma unroll
        for (int nt = 0; nt < 4; ++nt)
#pragma unroll
            for (int q = 0; q < 4; ++q)
                mt[lhi * 4 + q][16 * nt + lrow] =
                    (accA[nt][q] * sh0q[q] + accB[nt][q]) * INV_SQRT96;
#pragma unroll
        for (int nt = 0; nt < 2; ++nt)
#pragma unroll
            for (int q = 0; q < 4; ++q) {
                int w = 16 * nt + lrow, rr = lhi * 4 + q;
                float td = accD[nt][q];
                mt[rr][MUL_S + 3 * w + 0] = (accC0[nt][q] * sh0q[q] + td * sh1q[q][0]) * INV_S3S96;
                mt[rr][MUL_S + 3 * w + 1] = (accC1[nt][q] * sh0q[q] + td * sh1q[q][1]) * INV_S3S96;
                mt[rr][MUL_S + 3 * w + 2] = (accC2[nt][q] * sh0q[q] + td * sh1q[q][2]) * INV_S3S96;
            }
        __builtin_amdgcn_sched_barrier(0);   // mt writes precede scan reads

        // ---- segment scan over 16 rows, 160 cols / 64 lanes ----
        for (int c = lane; c < FEAT; c += 64) {
            float run = mt[0][c];
            int bprev = bs[0];
#pragma unroll
            for (int k = 1; k < 16; ++k) {
                int b = bs[k];
                if (b != bprev) {
                    atomicAdd(&m_acc[(size_t)bprev * FEAT + c], run);
                    run = 0.f; bprev = b;
                }
                run += mt[k][c];
            }
            atomicAdd(&m_acc[(size_t)bprev * FEAT + c], run);
        }
    }
}

// ---------------------------------------------------------------------------
// Phase 2 (tiny): out_virtual = (o3(x_virtual) + act(m*0.1))/sqrt(2)
// ---------------------------------------------------------------------------
__global__ __launch_bounds__(256) void phase2(
    const float* __restrict__ x_virtual,
    const float* __restrict__ Ws_vsc, const float* __restrict__ Wv_vsc,
    const float* __restrict__ m_acc,
    float* __restrict__ out_virtual)
{
    __shared__ float xs[32][FEAT + 4];
    const int block0 = blockIdx.x * 32;
    for (int idx = threadIdx.x; idx < 32 * FEAT; idx += 256) {
        int r = idx / FEAT, c = idx - r * FEAT;
        int n = block0 + r;
        xs[r][c] = (n < VN) ? x_virtual[(size_t)n * FEAT + c] : 0.f;
    }
    __syncthreads();
    const int r = threadIdx.x >> 3, g = threadIdx.x & 7, n = block0 + r;
    if (n >= VN) return;

    float acc_s[8] = {};
    for (int k = 0; k < MUL_S; ++k) {
        float xv = xs[r][k];
        const float* wrow = Ws_vsc + k * MUL_S + g * 8;
#pragma unroll
        for (int jj = 0; jj < 8; ++jj) acc_s[jj] = fmaf(xv, wrow[jj], acc_s[jj]);
    }
    float acc_v[4][3] = {};
    for (int u = 0; u < MUL_V; ++u) {
        float v0 = xs[r][MUL_S + 3 * u], v1 = xs[r][MUL_S + 3 * u + 1], v2 = xs[r][MUL_S + 3 * u + 2];
        const float* wrow = Wv_vsc + u * MUL_V + g * 4;
#pragma unroll
        for (int ww = 0; ww < 4; ++ww) {
            float wv = wrow[ww];
            acc_v[ww][0] = fmaf(v0, wv, acc_v[ww][0]);
            acc_v[ww][1] = fmaf(v1, wv, acc_v[ww][1]);
            acc_v[ww][2] = fmaf(v2, wv, acc_v[ww][2]);
        }
    }
    const float* mrow = m_acc + (size_t)n * FEAT;
    float* outrow = out_virtual + (size_t)n * FEAT;
#pragma unroll
    for (int jj = 0; jj < 8; ++jj) {
        int j = g * 8 + jj;
        outrow[j] = (acc_s[jj] * INV8 + silu_n(mrow[j] * INV_SQRT_AVG)) * INV_SQRT2;
    }
#pragma unroll
    for (int ww = 0; ww < 4; ++ww)
#pragma unroll
        for (int i = 0; i < 3; ++i) {
            int cc = MUL_S + (g * 4 + ww) * 3 + i;
            outrow[cc] = (acc_v[ww][i] * INV_SQRT32 + mrow[cc] * INV_SQRT_AVG) * INV_SQRT2;
        }
}

// ---------------------------------------------------------------------------
// K2: fused sn + gn + combine (UNCHANGED from R7 — measured fast; unroll-8
// staging avoids the spill cliff; full-unroll variants spilled: R4/R6).
// ---------------------------------------------------------------------------
__global__ __launch_bounds__(256, 2) void k2_out(
    const float* __restrict__ x_node, const float* __restrict__ out_virtual,
    const float* __restrict__ Ws_nsc, const float* __restrict__ Wv_nsc,
    const float* __restrict__ Ws_n2v, const float* __restrict__ Wv_n2v,
    const int* __restrict__ batch, float* __restrict__ out_node)
{
    __shared__ short xbf[64 * XSTR] __attribute__((aligned(16)));
    __shared__ short gbf[64 * XSTR] __attribute__((aligned(16)));
    __shared__ int   bs[64];

    const int lane = threadIdx.x & 63;
    const int lrow = lane & 15, lhi = lane >> 4;
    const int r0 = (threadIdx.x >> 6) * 16;

    bf16x8 bS1[4][2], bV1[2], bS2[4][2], bV2[2];
#pragma unroll
    for (int nt = 0; nt < 4; ++nt) {
        bS1[nt][0] = load_bfrag(Ws_nsc, 64, 0,  lrow + 16 * nt, lhi);
        bS1[nt][1] = load_bfrag(Ws_nsc, 64, 32, lrow + 16 * nt, lhi);
        bS2[nt][0] = load_bfrag(Ws_n2v, 64, 0,  lrow + 16 * nt, lhi);
        bS2[nt][1] = load_bfrag(Ws_n2v, 64, 32, lrow + 16 * nt, lhi);
    }
#pragma unroll
    for (int nt = 0; nt < 2; ++nt) {
        bV1[nt] = load_bfrag(Wv_nsc, 32, 0, lrow + 16 * nt, lhi);
        bV2[nt] = load_bfrag(Wv_n2v, 32, 0, lrow + 16 * nt, lhi);
    }

    for (int g0 = blockIdx.x; g0 < NN / 64; g0 += gridDim.x) {
        const int n0 = g0 * 64;
        __syncthreads();
        if (threadIdx.x < 64) bs[threadIdx.x] = batch[n0 + threadIdx.x];
        __syncthreads();
#pragma unroll 8
        for (int it = 0; it < 40; ++it) {
            int idx = threadIdx.x + it * 256;
            int row = idx / FEAT, col = idx - row * FEAT;
            int t = col - MUL_S;
            int dc = (col < MUL_S) ? col : MUL_S + (t % 3) * 32 + t / 3;
            xbf[row * XSTR + dc] = f2bf(x_node[(size_t)n0 * FEAT + idx]);
            gbf[row * XSTR + dc] = f2bf(out_virtual[(size_t)bs[row] * FEAT + col]);
        }
        __syncthreads();

        const int arow = (r0 + lrow) * XSTR + lhi * 8;
        bf16x8 axS0 = *(const bf16x8*)&xbf[arow];
        bf16x8 axS1 = *(const bf16x8*)&xbf[arow + 32];
        bf16x8 axV0 = *(const bf16x8*)&xbf[arow + 64];
        bf16x8 axV1 = *(const bf16x8*)&xbf[arow + 96];
        bf16x8 axV2 = *(const bf16x8*)&xbf[arow + 128];
        bf16x8 agS0 = *(const bf16x8*)&gbf[arow];
        bf16x8 agS1 = *(const bf16x8*)&gbf[arow + 32];
        bf16x8 agV0 = *(const bf16x8*)&gbf[arow + 64];
        bf16x8 agV1 = *(const bf16x8*)&gbf[arow + 96];
        bf16x8 agV2 = *(const bf16x8*)&gbf[arow + 128];

        // scalar output tiles
#pragma unroll
        for (int nt = 0; nt < 4; ++nt) {
            f32x4 sa = (f32x4){0,0,0,0}, ga = (f32x4){0,0,0,0};
            sa = MFMA(axS0, bS1[nt][0], sa); sa = MFMA(axS1, bS1[nt][1], sa);
            ga = MFMA(agS0, bS2[nt][0], ga); ga = MFMA(agS1, bS2[nt][1], ga);
#pragma unroll
            for (int q = 0; q < 4; ++q) {
                int gr = n0 + r0 + lhi * 4 + q;
                out_node[(size_t)gr * FEAT + 16 * nt + lrow] =
                    (sa[q] * INV8 + silu_n(ga[q] * INV8)) * INV_SQRT2;
            }
        }
        // vector output tiles (no act on v); both scaled INV_SQRT32
#pragma unroll
        for (int nt = 0; nt < 2; ++nt) {
            f32x4 s0 = (f32x4){0,0,0,0}, s1 = (f32x4){0,0,0,0}, s2 = (f32x4){0,0,0,0};
            f32x4 g0v = (f32x4){0,0,0,0}, g1 = (f32x4){0,0,0,0}, g2 = (f32x4){0,0,0,0};
            s0 = MFMA(axV0, bV1[nt], s0); s1 = MFMA(axV1, bV1[nt], s1); s2 = MFMA(axV2, bV1[nt], s2);
            g0v = MFMA(agV0, bV2[nt], g0v); g1 = MFMA(agV1, bV2[nt], g1); g2 = MFMA(agV2, bV2[nt], g2);
            const float sc = INV_SQRT32 * INV_SQRT2;
#pragma unroll
            for (int q = 0; q < 4; ++q) {
                int gr = n0 + r0 + lhi * 4 + q;
                int w = 16 * nt + lrow;
                float* op = out_node + (size_t)gr * FEAT + MUL_S + 3 * w;
                op[0] = (s0[q] + g0v[q]) * sc;
                op[1] = (s1[q] + g1[q]) * sc;
                op[2] = (s2[q] + g2[q]) * sc;
            }
        }
    }
}

// ---------------------------------------------------------------------------
extern "C" void kernel_launch(void* const* d_in, const int* in_sizes, int n_in,
                              void* d_out, int out_size, void* d_ws, size_t ws_size,
                              hipStream_t stream)
{
    const float* x_virtual = (const float*)d_in[0];
    const float* x_node    = (const float*)d_in[1];
    const float* sh        = (const float*)d_in[2];
    const float* Ws_vsc    = (const float*)d_in[3];
    const float* Wv_vsc    = (const float*)d_in[4];
    const float* Ws_nsc    = (const float*)d_in[5];
    const float* Wv_nsc    = (const float*)d_in[6];
    const float* WA        = (const float*)d_in[7];
    const float* WB        = (const float*)d_in[8];
    const float* WC        = (const float*)d_in[9];
    const float* WD        = (const float*)d_in[10];
    const float* Ws_n2v    = (const float*)d_in[11];
    const float* Wv_n2v    = (const float*)d_in[12];
    const int*   batch     = (const int*)d_in[13];

    float* out         = (float*)d_out;
    float* out_virtual = out;                 // [VN][FEAT]
    float* out_node    = out + VN * FEAT;     // [NN][FEAT]
    float* m_acc       = (float*)d_ws;        // [VN][FEAT]

    hipMemsetAsync(m_acc, 0, (size_t)VN * FEAT * sizeof(float), stream);

    k1_msg<<<2560, 64, 0, stream>>>(x_node, sh, WA, WB, WC, WD, batch, m_acc);
    phase2<<<(VN + 31) / 32, 256, 0, stream>>>(x_virtual, Ws_vsc, Wv_vsc,
                                               m_acc, out_virtual);
    k2_out<<<512, 256, 0, stream>>>(x_node, out_virtual, Ws_nsc, Wv_nsc,
                                    Ws_n2v, Wv_n2v, batch, out_node);
}

// Round 12
// 120.004 us; speedup vs baseline: 1.2491x; 1.2491x over previous
//
#include <hip/hip_runtime.h>
#include <math.h>

#define MUL_S 64
#define MUL_V 32
#define FEAT  160          // 64 + 3*32
#define VN    2000
#define NN    200000
#define NGRP16 (NN / 16)   // 12500 groups of 16 nodes (one wave each)
#define XSTR  168          // bf16 elems per LDS row (k2 only)

#define INV8         0.125f
#define INV_SQRT32   0.17677669529663687f
#define INV_SQRT3    0.57735026918962576f
#define INV_SQRT96   0.10206207261596575f
#define INV_S3S96    0.05892556509887896f   /* 1/(sqrt(3)*sqrt(96)) */
#define INV_SQRT2    0.70710678118654752f
#define INV_SQRT_AVG 0.1f

typedef __attribute__((ext_vector_type(8))) short bf16x8;   // 8 bf16 = 4 VGPR
typedef __attribute__((ext_vector_type(4))) float f32x4;    // acc frag

#define MFMA(a, b, c) __builtin_amdgcn_mfma_f32_16x16x32_bf16((a), (b), (c), 0, 0, 0)

__device__ __forceinline__ short f2bf(float f) {
    union { float f; unsigned u; } c; c.f = f;
    unsigned r = c.u + 0x7FFFu + ((c.u >> 16) & 1u);   // round-nearest-even
    return (short)(r >> 16);
}
__device__ __forceinline__ float bf2f(short s) {
    union { unsigned u; float f; } c; c.u = ((unsigned)(unsigned short)s) << 16;
    return c.f;
}
__device__ __forceinline__ float silu_n(float x) {
    return x * (1.0f / (1.0f + __expf(-x))) * 1.679059f;
}

// B-fragment for 16x16x32: lane holds col = (lane&15)+16*nt of W, k = lhi*8+e.
__device__ __forceinline__ bf16x8 load_bfrag(const float* __restrict__ W, int N,
                                             int kbase, int col, int lhi) {
    const float* p = W + (size_t)(kbase + lhi * 8) * N + col;
    bf16x8 b;
#pragma unroll
    for (int e = 0; e < 8; ++e) b[e] = f2bf(p[(size_t)e * N]);
    return b;
}

// ---------------------------------------------------------------------------
// K1 (R12): ZERO-LDS, zero-barrier. 1 wave / 16-node group.
// Falsified for k1: staging depth (R5/R7), LDS size (R8), scan cost (R9),
// HBM prefetch (R10), barriers (R11) — all 91-128us. Common element was the
// LDS round-trip chain; this version deletes it:
//  - A-frags loaded DIRECTLY from global: lane(lrow,lhi) reads contiguous
//    spans of row n0+lrow (10 float4). No xbf, no ds_read.
//  - Row scales folded into A-frags (scale A row r == scale D row r).
//  - Segment-sum via cross-lane: ~85% of tiles are segment-uniform
//    (batch[n0]==batch[n0+15], wave-uniform) -> sum q + 2 shfl_xor ->
//    one atomic per column from lhi==0 lanes. Slow path: per-lane run-merge.
// ---------------------------------------------------------------------------
__global__ __launch_bounds__(64) void k1_msg(
    const float* __restrict__ x_node, const float* __restrict__ sh,
    const float* __restrict__ WA, const float* __restrict__ WB,
    const float* __restrict__ WC, const float* __restrict__ WD,
    const int* __restrict__ batch, float* __restrict__ m_acc)
{
    const int lane = threadIdx.x;       // 0..63
    const int lrow = lane & 15, lhi = lane >> 4;

    bf16x8 bWA[4][2], bWB[4], bWC[2], bWD[2][2];
#pragma unroll
    for (int nt = 0; nt < 4; ++nt) {
        bWA[nt][0] = load_bfrag(WA, 64, 0,  lrow + 16 * nt, lhi);
        bWA[nt][1] = load_bfrag(WA, 64, 32, lrow + 16 * nt, lhi);
        bWB[nt]    = load_bfrag(WB, 64, 0,  lrow + 16 * nt, lhi);
    }
#pragma unroll
    for (int nt = 0; nt < 2; ++nt) {
        bWC[nt]    = load_bfrag(WC, 32, 0,  lrow + 16 * nt, lhi);
        bWD[nt][0] = load_bfrag(WD, 32, 0,  lrow + 16 * nt, lhi);
        bWD[nt][1] = load_bfrag(WD, 32, 32, lrow + 16 * nt, lhi);
    }

    for (int g0 = blockIdx.x; g0 < NGRP16; g0 += gridDim.x) {
        const int n0 = g0 * 16;
        const float* xrow = x_node + (size_t)(n0 + lrow) * FEAT;

        // ---- direct loads: this lane's A-frag data (row n0+lrow) ----
        float4 xq0 = *(const float4*)(xrow + lhi * 8);
        float4 xq1 = *(const float4*)(xrow + lhi * 8 + 4);
        float4 xq2 = *(const float4*)(xrow + 32 + lhi * 8);
        float4 xq3 = *(const float4*)(xrow + 32 + lhi * 8 + 4);
        float4 vq0 = *(const float4*)(xrow + 64 + 24 * lhi);
        float4 vq1 = *(const float4*)(xrow + 64 + 24 * lhi + 4);
        float4 vq2 = *(const float4*)(xrow + 64 + 24 * lhi + 8);
        float4 vq3 = *(const float4*)(xrow + 64 + 24 * lhi + 12);
        float4 vq4 = *(const float4*)(xrow + 64 + 24 * lhi + 16);
        float4 vq5 = *(const float4*)(xrow + 64 + 24 * lhi + 20);
        float4 shr = *(const float4*)(sh + (size_t)(n0 + lrow) * 4);
        float4 sh4[4];
#pragma unroll
        for (int q = 0; q < 4; ++q)
            sh4[q] = *(const float4*)(sh + (size_t)(n0 + lhi * 4 + q) * 4);
        const int b_lo = batch[n0];
        const int b_hi = batch[n0 + 15];
        const int4 bq4 = *(const int4*)(batch + n0 + lhi * 4);

        // ---- build A-frags (scales folded: sh0 into rows) ----
        const float sh0 = shr.x;
        float vf[24];
        *(float4*)&vf[0]  = vq0; *(float4*)&vf[4]  = vq1;
        *(float4*)&vf[8]  = vq2; *(float4*)&vf[12] = vq3;
        *(float4*)&vf[16] = vq4; *(float4*)&vf[20] = vq5;

        bf16x8 aS0, aS1, aS0s, aS1s, aV0s, aV1s, aV2s, aDot;
#pragma unroll
        for (int e = 0; e < 4; ++e) {
            float a = (&xq0.x)[e], b = (&xq1.x)[e];
            float c = (&xq2.x)[e], d = (&xq3.x)[e];
            aS0[e]     = f2bf(a);        aS0[e + 4] = f2bf(b);
            aS1[e]     = f2bf(c);        aS1[e + 4] = f2bf(d);
            aS0s[e]    = f2bf(a * sh0);  aS0s[e + 4] = f2bf(b * sh0);
            aS1s[e]    = f2bf(c * sh0);  aS1s[e + 4] = f2bf(d * sh0);
        }
#pragma unroll
        for (int e = 0; e < 8; ++e) {
            float v0 = vf[3 * e], v1 = vf[3 * e + 1], v2 = vf[3 * e + 2];
            aV0s[e] = f2bf(v0 * sh0);
            aV1s[e] = f2bf(v1 * sh0);
            aV2s[e] = f2bf(v2 * sh0);
            aDot[e] = f2bf((v0 * shr.y + v1 * shr.z + v2 * shr.w) * INV_SQRT3);
        }

        // ---- MFMA: scalar chain fully folded; accD separate (sh1_i post) ----
        f32x4 accS[4], accD[2], accC[2][3];
#pragma unroll
        for (int nt = 0; nt < 4; ++nt) {
            f32x4 a = MFMA(aDot, bWB[nt], ((f32x4){0.f, 0.f, 0.f, 0.f}));
            a = MFMA(aS0s, bWA[nt][0], a);
            a = MFMA(aS1s, bWA[nt][1], a);
            accS[nt] = a;
        }
#pragma unroll
        for (int nt = 0; nt < 2; ++nt) {
            f32x4 d = MFMA(aS1, bWD[nt][1], ((f32x4){0.f, 0.f, 0.f, 0.f}));
            d = MFMA(aS0, bWD[nt][0], d);
            accD[nt] = d;
            accC[nt][0] = MFMA(aV0s, bWC[nt], ((f32x4){0.f, 0.f, 0.f, 0.f}));
            accC[nt][1] = MFMA(aV1s, bWC[nt], ((f32x4){0.f, 0.f, 0.f, 0.f}));
            accC[nt][2] = MFMA(aV2s, bWC[nt], ((f32x4){0.f, 0.f, 0.f, 0.f}));
        }

        // ---- segment-sum + atomics (D rows = lhi*4+q, col = 16*nt+lrow) ----
        if (b_lo == b_hi) {
            // FAST: whole tile one segment. Column sum via q-sum + shfl over lhi.
#pragma unroll
            for (int nt = 0; nt < 4; ++nt) {
                float s = (accS[nt][0] + accS[nt][1] + accS[nt][2] + accS[nt][3])
                          * INV_SQRT96;
                s += __shfl_xor(s, 16, 64);
                s += __shfl_xor(s, 32, 64);
                if (lhi == 0)
                    atomicAdd(&m_acc[(size_t)b_lo * FEAT + 16 * nt + lrow], s);
            }
#pragma unroll
            for (int nt = 0; nt < 2; ++nt)
#pragma unroll
                for (int i = 0; i < 3; ++i) {
                    float s = 0.f;
#pragma unroll
                    for (int q = 0; q < 4; ++q)
                        s += accC[nt][i][q] + accD[nt][q] * (&sh4[q].y)[i];
                    s *= INV_S3S96;
                    s += __shfl_xor(s, 16, 64);
                    s += __shfl_xor(s, 32, 64);
                    if (lhi == 0)
                        atomicAdd(&m_acc[(size_t)b_lo * FEAT + MUL_S
                                         + 3 * (16 * nt + lrow) + i], s);
                }
        } else {
            // SLOW (~15%): per-lane run-merge over its 4 rows.
            const int bqa[4] = { bq4.x, bq4.y, bq4.z, bq4.w };
#pragma unroll
            for (int nt = 0; nt < 4; ++nt) {
                const int col = 16 * nt + lrow;
                float run = accS[nt][0] * INV_SQRT96;
                int bp = bqa[0];
#pragma unroll
                for (int q = 1; q < 4; ++q) {
                    float v = accS[nt][q] * INV_SQRT96;
                    if (bqa[q] != bp) {
                        atomicAdd(&m_acc[(size_t)bp * FEAT + col], run);
                        run = 0.f; bp = bqa[q];
                    }
                    run += v;
                }
                atomicAdd(&m_acc[(size_t)bp * FEAT + col], run);
            }
#pragma unroll
            for (int nt = 0; nt < 2; ++nt)
#pragma unroll
                for (int i = 0; i < 3; ++i) {
                    const int col = MUL_S + 3 * (16 * nt + lrow) + i;
                    float run = (accC[nt][i][0] + accD[nt][0] * (&sh4[0].y)[i])
                                * INV_S3S96;
                    int bp = bqa[0];
#pragma unroll
                    for (int q = 1; q < 4; ++q) {
                        float v = (accC[nt][i][q] + accD[nt][q] * (&sh4[q].y)[i])
                                  * INV_S3S96;
                        if (bqa[q] != bp) {
                            atomicAdd(&m_acc[(size_t)bp * FEAT + col], run);
                            run = 0.f; bp = bqa[q];
                        }
                        run += v;
                    }
                    atomicAdd(&m_acc[(size_t)bp * FEAT + col], run);
                }
        }
    }
}

// ---------------------------------------------------------------------------
// Phase 2 (tiny): out_virtual = (o3(x_virtual) + act(m*0.1))/sqrt(2)
// ---------------------------------------------------------------------------
__global__ __launch_bounds__(256) void phase2(
    const float* __restrict__ x_virtual,
    const float* __restrict__ Ws_vsc, const float* __restrict__ Wv_vsc,
    const float* __restrict__ m_acc,
    float* __restrict__ out_virtual)
{
    __shared__ float xs[32][FEAT + 4];
    const int block0 = blockIdx.x * 32;
    for (int idx = threadIdx.x; idx < 32 * FEAT; idx += 256) {
        int r = idx / FEAT, c = idx - r * FEAT;
        int n = block0 + r;
        xs[r][c] = (n < VN) ? x_virtual[(size_t)n * FEAT + c] : 0.f;
    }
    __syncthreads();
    const int r = threadIdx.x >> 3, g = threadIdx.x & 7, n = block0 + r;
    if (n >= VN) return;

    float acc_s[8] = {};
    for (int k = 0; k < MUL_S; ++k) {
        float xv = xs[r][k];
        const float* wrow = Ws_vsc + k * MUL_S + g * 8;
#pragma unroll
        for (int jj = 0; jj < 8; ++jj) acc_s[jj] = fmaf(xv, wrow[jj], acc_s[jj]);
    }
    float acc_v[4][3] = {};
    for (int u = 0; u < MUL_V; ++u) {
        float v0 = xs[r][MUL_S + 3 * u], v1 = xs[r][MUL_S + 3 * u + 1], v2 = xs[r][MUL_S + 3 * u + 2];
        const float* wrow = Wv_vsc + u * MUL_V + g * 4;
#pragma unroll
        for (int ww = 0; ww < 4; ++ww) {
            float wv = wrow[ww];
            acc_v[ww][0] = fmaf(v0, wv, acc_v[ww][0]);
            acc_v[ww][1] = fmaf(v1, wv, acc_v[ww][1]);
            acc_v[ww][2] = fmaf(v2, wv, acc_v[ww][2]);
        }
    }
    const float* mrow = m_acc + (size_t)n * FEAT;
    float* outrow = out_virtual + (size_t)n * FEAT;
#pragma unroll
    for (int jj = 0; jj < 8; ++jj) {
        int j = g * 8 + jj;
        outrow[j] = (acc_s[jj] * INV8 + silu_n(mrow[j] * INV_SQRT_AVG)) * INV_SQRT2;
    }
#pragma unroll
    for (int ww = 0; ww < 4; ++ww)
#pragma unroll
        for (int i = 0; i < 3; ++i) {
            int cc = MUL_S + (g * 4 + ww) * 3 + i;
            outrow[cc] = (acc_v[ww][i] * INV_SQRT32 + mrow[cc] * INV_SQRT_AVG) * INV_SQRT2;
        }
}

// ---------------------------------------------------------------------------
// K2: fused sn + gn + combine (UNCHANGED from R7 — measured fast; unroll-8
// staging avoids the spill cliff; full-unroll variants spilled: R4/R6).
// ---------------------------------------------------------------------------
__global__ __launch_bounds__(256, 2) void k2_out(
    const float* __restrict__ x_node, const float* __restrict__ out_virtual,
    const float* __restrict__ Ws_nsc, const float* __restrict__ Wv_nsc,
    const float* __restrict__ Ws_n2v, const float* __restrict__ Wv_n2v,
    const int* __restrict__ batch, float* __restrict__ out_node)
{
    __shared__ short xbf[64 * XSTR] __attribute__((aligned(16)));
    __shared__ short gbf[64 * XSTR] __attribute__((aligned(16)));
    __shared__ int   bs[64];

    const int lane = threadIdx.x & 63;
    const int lrow = lane & 15, lhi = lane >> 4;
    const int r0 = (threadIdx.x >> 6) * 16;

    bf16x8 bS1[4][2], bV1[2], bS2[4][2], bV2[2];
#pragma unroll
    for (int nt = 0; nt < 4; ++nt) {
        bS1[nt][0] = load_bfrag(Ws_nsc, 64, 0,  lrow + 16 * nt, lhi);
        bS1[nt][1] = load_bfrag(Ws_nsc, 64, 32, lrow + 16 * nt, lhi);
        bS2[nt][0] = load_bfrag(Ws_n2v, 64, 0,  lrow + 16 * nt, lhi);
        bS2[nt][1] = load_bfrag(Ws_n2v, 64, 32, lrow + 16 * nt, lhi);
    }
#pragma unroll
    for (int nt = 0; nt < 2; ++nt) {
        bV1[nt] = load_bfrag(Wv_nsc, 32, 0, lrow + 16 * nt, lhi);
        bV2[nt] = load_bfrag(Wv_n2v, 32, 0, lrow + 16 * nt, lhi);
    }

    for (int g0 = blockIdx.x; g0 < NN / 64; g0 += gridDim.x) {
        const int n0 = g0 * 64;
        __syncthreads();
        if (threadIdx.x < 64) bs[threadIdx.x] = batch[n0 + threadIdx.x];
        __syncthreads();
#pragma unroll 8
        for (int it = 0; it < 40; ++it) {
            int idx = threadIdx.x + it * 256;
            int row = idx / FEAT, col = idx - row * FEAT;
            int t = col - MUL_S;
            int dc = (col < MUL_S) ? col : MUL_S + (t % 3) * 32 + t / 3;
            xbf[row * XSTR + dc] = f2bf(x_node[(size_t)n0 * FEAT + idx]);
            gbf[row * XSTR + dc] = f2bf(out_virtual[(size_t)bs[row] * FEAT + col]);
        }
        __syncthreads();

        const int arow = (r0 + lrow) * XSTR + lhi * 8;
        bf16x8 axS0 = *(const bf16x8*)&xbf[arow];
        bf16x8 axS1 = *(const bf16x8*)&xbf[arow + 32];
        bf16x8 axV0 = *(const bf16x8*)&xbf[arow + 64];
        bf16x8 axV1 = *(const bf16x8*)&xbf[arow + 96];
        bf16x8 axV2 = *(const bf16x8*)&xbf[arow + 128];
        bf16x8 agS0 = *(const bf16x8*)&gbf[arow];
        bf16x8 agS1 = *(const bf16x8*)&gbf[arow + 32];
        bf16x8 agV0 = *(const bf16x8*)&gbf[arow + 64];
        bf16x8 agV1 = *(const bf16x8*)&gbf[arow + 96];
        bf16x8 agV2 = *(const bf16x8*)&gbf[arow + 128];

        // scalar output tiles
#pragma unroll
        for (int nt = 0; nt < 4; ++nt) {
            f32x4 sa = (f32x4){0,0,0,0}, ga = (f32x4){0,0,0,0};
            sa = MFMA(axS0, bS1[nt][0], sa); sa = MFMA(axS1, bS1[nt][1], sa);
            ga = MFMA(agS0, bS2[nt][0], ga); ga = MFMA(agS1, bS2[nt][1], ga);
#pragma unroll
            for (int q = 0; q < 4; ++q) {
                int gr = n0 + r0 + lhi * 4 + q;
                out_node[(size_t)gr * FEAT + 16 * nt + lrow] =
                    (sa[q] * INV8 + silu_n(ga[q] * INV8)) * INV_SQRT2;
            }
        }
        // vector output tiles (no act on v); both scaled INV_SQRT32
#pragma unroll
        for (int nt = 0; nt < 2; ++nt) {
            f32x4 s0 = (f32x4){0,0,0,0}, s1 = (f32x4){0,0,0,0}, s2 = (f32x4){0,0,0,0};
            f32x4 g0v = (f32x4){0,0,0,0}, g1 = (f32x4){0,0,0,0}, g2 = (f32x4){0,0,0,0};
            s0 = MFMA(axV0, bV1[nt], s0); s1 = MFMA(axV1, bV1[nt], s1); s2 = MFMA(axV2, bV1[nt], s2);
            g0v = MFMA(agV0, bV2[nt], g0v); g1 = MFMA(agV1, bV2[nt], g1); g2 = MFMA(agV2, bV2[nt], g2);
            const float sc = INV_SQRT32 * INV_SQRT2;
#pragma unroll
            for (int q = 0; q < 4; ++q) {
                int gr = n0 + r0 + lhi * 4 + q;
                int w = 16 * nt + lrow;
                float* op = out_node + (size_t)gr * FEAT + MUL_S + 3 * w;
                op[0] = (s0[q] + g0v[q]) * sc;
                op[1] = (s1[q] + g1[q]) * sc;
                op[2] = (s2[q] + g2[q]) * sc;
            }
        }
    }
}

// ---------------------------------------------------------------------------
extern "C" void kernel_launch(void* const* d_in, const int* in_sizes, int n_in,
                              void* d_out, int out_size, void* d_ws, size_t ws_size,
                              hipStream_t stream)
{
    const float* x_virtual = (const float*)d_in[0];
    const float* x_node    = (const float*)d_in[1];
    const float* sh        = (const float*)d_in[2];
    const float* Ws_vsc    = (const float*)d_in[3];
    const float* Wv_vsc    = (const float*)d_in[4];
    const float* Ws_nsc    = (const float*)d_in[5];
    const float* Wv_nsc    = (const float*)d_in[6];
    const float* WA        = (const float*)d_in[7];
    const float* WB        = (const float*)d_in[8];
    const float* WC        = (const float*)d_in[9];
    const float* WD        = (const float*)d_in[10];
    const float* Ws_n2v    = (const float*)d_in[11];
    const float* Wv_n2v    = (const float*)d_in[12];
    const int*   batch     = (const int*)d_in[13];

    float* out         = (float*)d_out;
    float* out_virtual = out;                 // [VN][FEAT]
    float* out_node    = out + VN * FEAT;     // [NN][FEAT]
    float* m_acc       = (float*)d_ws;        // [VN][FEAT]

    hipMemsetAsync(m_acc, 0, (size_t)VN * FEAT * sizeof(float), stream);

    k1_msg<<<2048, 64, 0, stream>>>(x_node, sh, WA, WB, WC, WD, batch, m_acc);
    phase2<<<(VN + 31) / 32, 256, 0, stream>>>(x_virtual, Ws_vsc, Wv_vsc,
                                               m_acc, out_virtual);
    k2_out<<<512, 256, 0, stream>>>(x_node, out_virtual, Ws_nsc, Wv_nsc,
                                    Ws_n2v, Wv_n2v, batch, out_node);
}